// Round 1
// baseline (7083.958 us; speedup 1.0000x reference)
//
#include <hip/hip_runtime.h>
#include <math.h>

// NERBertWithCRF — round 5: GEMMs moved to MFMA via f16 hi/lo split (3-term
// fp32 emulation: Ahi*Whi + Ahi*Wlo + Alo*Whi, f32 accumulate).
// Residual ~2^-22 relative => decode-safe (f32-reorder-grade noise).
// All non-GEMM math stays f32 (attn, LN, CRF, head) for exactness.

#define Bz 32
#define Lz 128
#define DMz 768
#define NLz 12
#define NHz 12
#define DHz 64
#define FFz 3072
#define Kz 9
#define Tz 127
#define RR (Bz * Lz) // 4096 rows
#define QKVP 2304    // fused QKV output pitch

typedef float f32x4v __attribute__((ext_vector_type(4)));
typedef _Float16 f16x8v __attribute__((ext_vector_type(8)));

__device__ __forceinline__ float wred(float v) {
#pragma unroll
    for (int o = 32; o > 0; o >>= 1) v += __shfl_down(v, o, 64);
    return v;
}

__global__ void sentinel_k(float* out) {
    if (threadIdx.x == 0) out[0] = 123456.0f;
}

// ---------------- embedding + LayerNorm ----------------
__global__ __launch_bounds__(256) void embed_ln_k(
    const int* __restrict__ ids, const int* __restrict__ tts,
    const float* __restrict__ we, const float* __restrict__ pe, const float* __restrict__ te,
    const float* __restrict__ g, const float* __restrict__ bb, float* __restrict__ X)
{
    int r = blockIdx.x;
    int pos = r & (Lz - 1);
    int tid = threadIdx.x;
    int id = ids[r], tt = tts[r];
    __shared__ float buf[DMz];
    __shared__ float sa[4], sb[4];
    float s = 0.f, s2 = 0.f;
    for (int d = tid; d < DMz; d += 256) {
        float v = we[(size_t)id * DMz + d] + pe[pos * DMz + d] + te[tt * DMz + d];
        buf[d] = v; s += v; s2 += v * v;
    }
    float w1 = wred(s), w2 = wred(s2);
    if ((tid & 63) == 0) { sa[tid >> 6] = w1; sb[tid >> 6] = w2; }
    __syncthreads();
    float S = sa[0] + sa[1] + sa[2] + sa[3];
    float S2 = sb[0] + sb[1] + sb[2] + sb[3];
    float mean = S * (1.f / DMz);
    float var = S2 * (1.f / DMz) - mean * mean;
    float inv = rsqrtf(var + 1e-12f);
    for (int d = tid; d < DMz; d += 256)
        X[(size_t)r * DMz + d] = (buf[d] - mean) * inv * g[d] + bb[d];
}

// ---------------- residual add + LayerNorm (in-place into X) ----------------
__global__ __launch_bounds__(256) void addln_k(
    float* __restrict__ X, const float* __restrict__ Y,
    const float* __restrict__ g, const float* __restrict__ bb)
{
    int r = blockIdx.x;
    int tid = threadIdx.x;
    __shared__ float buf[DMz];
    __shared__ float sa[4], sb2[4];
    size_t base = (size_t)r * DMz;
    float s = 0.f, s2 = 0.f;
    for (int d = tid; d < DMz; d += 256) {
        float v = X[base + d] + Y[base + d];
        buf[d] = v; s += v; s2 += v * v;
    }
    float w1 = wred(s), w2 = wred(s2);
    if ((tid & 63) == 0) { sa[tid >> 6] = w1; sb2[tid >> 6] = w2; }
    __syncthreads();
    float S = sa[0] + sa[1] + sa[2] + sa[3];
    float S2 = sb2[0] + sb2[1] + sb2[2] + sb2[3];
    float mean = S * (1.f / DMz);
    float var = S2 * (1.f / DMz) - mean * mean;
    float inv = rsqrtf(var + 1e-12f);
    for (int d = tid; d < DMz; d += 256)
        X[base + d] = (buf[d] - mean) * inv * g[d] + bb[d];
}

// ---------------- QKV bias concat (all layers, once) ----------------
__global__ __launch_bounds__(256) void bbfill_k(
    const float* __restrict__ bq, const float* __restrict__ bk,
    const float* __restrict__ bv, float* __restrict__ BB)
{
    int i = blockIdx.x * 256 + threadIdx.x;
    if (i >= NLz * QKVP) return;
    int l = i / QKVP, j = i - l * QKVP;
    float v;
    if (j < 768) v = bq[l * 768 + j];
    else if (j < 1536) v = bk[l * 768 + j - 768];
    else v = bv[l * 768 + j - 1536];
    BB[i] = v;
}

// ---------------- weight transpose + f16 hi/lo split ----------------
// W [Kt][Nt] f32 (row pitch ldw) -> oh/ol [orow0+Nt][Kt] f16 (row pitch opitch)
__global__ __launch_bounds__(256) void wt_k(
    const float* __restrict__ W, int ldw, int Kt, int Nt,
    _Float16* __restrict__ oh, _Float16* __restrict__ ol, int orow0, int opitch)
{
    (void)Kt; (void)Nt;
    __shared__ float LS[64][65];
    int n0 = blockIdx.x * 64, k0 = blockIdx.y * 64;
    int t = threadIdx.x;
    // load phase: 64(k) x 64(n) tile, coalesced along n
    int kr = t >> 2, nc = (t & 3) * 16;
    const float* wp = W + (size_t)(k0 + kr) * ldw + n0 + nc;
    float4 v0 = *(const float4*)(wp);
    float4 v1 = *(const float4*)(wp + 4);
    float4 v2 = *(const float4*)(wp + 8);
    float4 v3 = *(const float4*)(wp + 12);
    float* lsp = &LS[kr][nc];
    lsp[0] = v0.x; lsp[1] = v0.y; lsp[2] = v0.z; lsp[3] = v0.w;
    lsp[4] = v1.x; lsp[5] = v1.y; lsp[6] = v1.z; lsp[7] = v1.w;
    lsp[8] = v2.x; lsp[9] = v2.y; lsp[10] = v2.z; lsp[11] = v2.w;
    lsp[12] = v3.x; lsp[13] = v3.y; lsp[14] = v3.z; lsp[15] = v3.w;
    __syncthreads();
    // store phase: transposed, split, coalesced along k
    int n = t >> 2, kq = (t & 3) * 16;
    __align__(16) _Float16 hh[16], ll[16];
#pragma unroll
    for (int j = 0; j < 16; j++) {
        float v = LS[kq + j][n];
        _Float16 h = (_Float16)v;
        hh[j] = h;
        ll[j] = (_Float16)(v - (float)h);
    }
    size_t ob = (size_t)(orow0 + n0 + n) * opitch + k0 + kq;
    *(uint4*)&oh[ob]     = *(uint4*)&hh[0];
    *(uint4*)&oh[ob + 8] = *(uint4*)&hh[8];
    *(uint4*)&ol[ob]     = *(uint4*)&ll[0];
    *(uint4*)&ol[ob + 8] = *(uint4*)&ll[8];
}

// ---------------- MFMA GEMM: C = [accum +] act(A @ W + bias) ----------------
// A f32 [M][Kd] (pitch lda); Wh/Wl f16 [N][Kd] (pitch Kd, pre-transposed+split)
// tile 128x128x32, 256 threads (4 waves, 64x64 each), mfma_f32_16x16x32_f16 x3
__global__ __launch_bounds__(256) void gemm_mx_k(
    const float* __restrict__ A, int lda,
    const _Float16* __restrict__ Wh, const _Float16* __restrict__ Wl,
    const float* __restrict__ bias, float* __restrict__ C, int ldc,
    int Kd, int act, int accum)
{
    __shared__ _Float16 Ahs[128][40];
    __shared__ _Float16 Als[128][40];
    __shared__ _Float16 Bhs[128][40];
    __shared__ _Float16 Bls[128][40];
    int tid = threadIdx.x;
    int lane = tid & 63, wid = tid >> 6;
    int wr = wid >> 1, wc = wid & 1;
    int row0 = blockIdx.y * 128, col0 = blockIdx.x * 128;
    int sr = tid >> 1;             // staging row (A row / C col) 0..127
    int sk = (tid & 1) << 4;       // staging k offset 0 / 16

    const float* ap = A + (size_t)(row0 + sr) * lda + sk;
    const _Float16* whp = Wh + (size_t)(col0 + sr) * Kd + sk;
    const _Float16* wlp = Wl + (size_t)(col0 + sr) * Kd + sk;

    f32x4v acc[4][4];
#pragma unroll
    for (int i = 0; i < 4; i++)
#pragma unroll
        for (int j = 0; j < 4; j++) acc[i][j] = (f32x4v)0.f;

    __align__(16) float av[16];
    uint4 bhr0, bhr1, blr0, blr1;
#define LOADAB(ko) do { \
        *(float4*)&av[0]  = *(const float4*)(ap + (ko)); \
        *(float4*)&av[4]  = *(const float4*)(ap + (ko) + 4); \
        *(float4*)&av[8]  = *(const float4*)(ap + (ko) + 8); \
        *(float4*)&av[12] = *(const float4*)(ap + (ko) + 12); \
        bhr0 = *(const uint4*)(whp + (ko)); \
        bhr1 = *(const uint4*)(whp + (ko) + 8); \
        blr0 = *(const uint4*)(wlp + (ko)); \
        blr1 = *(const uint4*)(wlp + (ko) + 8); \
    } while (0)

    LOADAB(0);
    int nk = Kd >> 5;
    int arow = wr * 64 + (lane & 15);
    int bcol = wc * 64 + (lane & 15);
    int kb = (lane >> 4) << 3;

    for (int kt = 0; kt < nk; ++kt) {
        __syncthreads();   // previous compute done reading LDS
        {
            __align__(16) _Float16 hh[16], ll[16];
#pragma unroll
            for (int i = 0; i < 16; i++) {
                _Float16 h = (_Float16)av[i];
                hh[i] = h;
                ll[i] = (_Float16)(av[i] - (float)h);
            }
            *(uint4*)&Ahs[sr][sk]     = *(uint4*)&hh[0];
            *(uint4*)&Ahs[sr][sk + 8] = *(uint4*)&hh[8];
            *(uint4*)&Als[sr][sk]     = *(uint4*)&ll[0];
            *(uint4*)&Als[sr][sk + 8] = *(uint4*)&ll[8];
            *(uint4*)&Bhs[sr][sk]     = bhr0;
            *(uint4*)&Bhs[sr][sk + 8] = bhr1;
            *(uint4*)&Bls[sr][sk]     = blr0;
            *(uint4*)&Bls[sr][sk + 8] = blr1;
        }
        __syncthreads();   // LDS ready
        if (kt + 1 < nk) { LOADAB((kt + 1) << 5); }  // prefetch hides under MFMA

        f16x8v afh[4], afl[4];
#pragma unroll
        for (int mi = 0; mi < 4; mi++) {
            afh[mi] = *(const f16x8v*)&Ahs[arow + mi * 16][kb];
            afl[mi] = *(const f16x8v*)&Als[arow + mi * 16][kb];
        }
#pragma unroll
        for (int ni = 0; ni < 4; ni++) {
            f16x8v bfh = *(const f16x8v*)&Bhs[bcol + ni * 16][kb];
            f16x8v bfl = *(const f16x8v*)&Bls[bcol + ni * 16][kb];
#pragma unroll
            for (int mi = 0; mi < 4; mi++) {
                acc[mi][ni] = __builtin_amdgcn_mfma_f32_16x16x32_f16(afh[mi], bfh, acc[mi][ni], 0, 0, 0);
                acc[mi][ni] = __builtin_amdgcn_mfma_f32_16x16x32_f16(afh[mi], bfl, acc[mi][ni], 0, 0, 0);
                acc[mi][ni] = __builtin_amdgcn_mfma_f32_16x16x32_f16(afl[mi], bfh, acc[mi][ni], 0, 0, 0);
            }
        }
    }
#undef LOADAB

    // epilogue: C/D layout (16x16): col = lane&15, row = (lane>>4)*4 + reg
    int rb2 = (lane >> 4) << 2;
    int cb = lane & 15;
#pragma unroll
    for (int mi = 0; mi < 4; mi++) {
#pragma unroll
        for (int ni = 0; ni < 4; ni++) {
            int cc = col0 + wc * 64 + ni * 16 + cb;
            float bv = bias ? bias[cc] : 0.f;
#pragma unroll
            for (int r = 0; r < 4; r++) {
                int rr = row0 + wr * 64 + mi * 16 + rb2 + r;
                float v = acc[mi][ni][r] + bv;
                if (act == 1) v = 0.5f * v * (1.0f + erff(v * 0.70710678118f));
                size_t o = (size_t)rr * ldc + cc;
                if (accum) v += C[o];
                C[o] = v;
            }
        }
    }
}

// ---------------- attention: flash-style, one block per (b,h) ----------------
// Q/K/V fused buffer, pitch QKVP, col offsets 0/768/1536. Pure f32 (decode-safe).
__global__ __launch_bounds__(128) void attn_k(
    const float* __restrict__ QKV, const int* __restrict__ am, float* __restrict__ CTX)
{
    int bh = blockIdx.x;
    int b = bh / NHz, h = bh - b * NHz;
    __shared__ float Ks[64][DHz];
    __shared__ float Vs[64][DHz];
    int tid = threadIdx.x;
    float qreg[DHz];
    {
        const float* qp = QKV + (size_t)(b * Lz + tid) * QKVP + h * DHz;
#pragma unroll
        for (int d = 0; d < DHz; d++) qreg[d] = qp[d];
    }
    float m = -INFINITY, l = 0.f;
    float ctx[DHz];
#pragma unroll
    for (int d = 0; d < DHz; d++) ctx[d] = 0.f;
    for (int kc = 0; kc < Lz; kc += 64) {
        __syncthreads();
        for (int i = tid; i < 64 * DHz; i += 128) {
            int kk = i >> 6, d = i & 63;
            size_t base = (size_t)(b * Lz + kc + kk) * QKVP + h * DHz + d;
            Ks[kk][d] = QKV[base + 768];
            Vs[kk][d] = QKV[base + 1536];
        }
        __syncthreads();
        for (int k = 0; k < 64; k++) {
            float s = 0.f;
#pragma unroll
            for (int d = 0; d < DHz; d++) s = fmaf(qreg[d], Ks[k][d], s);
            s = s * 0.125f + (1.0f - (float)am[b * Lz + kc + k]) * -1e9f;
            float nm = fmaxf(m, s);
            float alpha = __expf(m - nm);
            float p = __expf(s - nm);
            l = l * alpha + p;
#pragma unroll
            for (int d = 0; d < DHz; d++) ctx[d] = ctx[d] * alpha + p * Vs[k][d];
            m = nm;
        }
    }
    float inv = 1.0f / l;
    float* cp = CTX + (size_t)(b * Lz + tid) * DMz + h * DHz;
#pragma unroll
    for (int d = 0; d < DHz; d++) cp[d] = ctx[d] * inv;
}

// ---------------- head: em[b,t,:] = x[b,t+1,:] @ head_W + head_b ----------------
__global__ __launch_bounds__(64) void head_k(
    const float* __restrict__ X, const float* __restrict__ hW, const float* __restrict__ hb,
    float* __restrict__ EM)
{
    int rt = blockIdx.x;
    int b = rt / Tz, t = rt - b * Tz;
    int lane = threadIdx.x;
    const float* xp = X + (size_t)(b * Lz + t + 1) * DMz;
    float acc[Kz];
#pragma unroll
    for (int k = 0; k < Kz; k++) acc[k] = 0.f;
    for (int d = lane; d < DMz; d += 64) {
        float xv = xp[d];
#pragma unroll
        for (int k = 0; k < Kz; k++) acc[k] = fmaf(xv, hW[d * Kz + k], acc[k]);
    }
#pragma unroll
    for (int k = 0; k < Kz; k++) acc[k] = wred(acc[k]);
    if (lane == 0) {
#pragma unroll
        for (int k = 0; k < Kz; k++) EM[(size_t)rt * Kz + k] = acc[k] + hb[k];
    }
}

// ---------------- CRF: lanes 0..31 = forward/llh, lanes 64..95 = viterbi ----------------
__global__ __launch_bounds__(128) void crf_k(
    const float* __restrict__ EM, const int* __restrict__ yt, const int* __restrict__ am,
    const float* __restrict__ cs, const float* __restrict__ ce, const float* __restrict__ ctr,
    int* __restrict__ hist, float* __restrict__ out)
{
    __shared__ float tr[Kz * Kz], st[Kz], en[Kz], nums[Bz], Zs[Bz];
    int tid = threadIdx.x;
    if (tid < Kz * Kz) tr[tid] = ctr[tid];
    if (tid < Kz) { st[tid] = cs[tid]; en[tid] = ce[tid]; }
    __syncthreads();
    if (tid < Bz) {
        int b = tid;
        const float* em = EM + (size_t)b * Tz * Kz;
        const int* y = yt + b * Tz;
        const int* mr = am + b * Lz;
        float num = st[y[0]] + em[y[0]];
        for (int t = 1; t < Tz; t++) {
            float mf = (mr[t + 1] != 0) ? 1.f : 0.f;
            num += (tr[y[t - 1] * Kz + y[t]] + em[t * Kz + y[t]]) * mf;
        }
        int lastidx = -1;
        for (int t = 0; t < Tz; t++) lastidx += (mr[t + 1] != 0) ? 1 : 0;
        num += en[y[lastidx]];
        nums[b] = num;
        float alpha[Kz];
#pragma unroll
        for (int j = 0; j < Kz; j++) alpha[j] = st[j] + em[j];
        for (int t = 1; t < Tz; t++) {
            bool mm = mr[t + 1] != 0;
            float nxt[Kz];
            for (int j = 0; j < Kz; j++) {
                float mx = -1e30f;
                for (int i = 0; i < Kz; i++) mx = fmaxf(mx, alpha[i] + tr[i * Kz + j]);
                float sm = 0.f;
                for (int i = 0; i < Kz; i++) sm += expf(alpha[i] + tr[i * Kz + j] - mx);
                nxt[j] = mx + logf(sm) + em[t * Kz + j];
            }
            if (mm) { for (int j = 0; j < Kz; j++) alpha[j] = nxt[j]; }
        }
        float mx = -1e30f;
        for (int j = 0; j < Kz; j++) mx = fmaxf(mx, alpha[j] + en[j]);
        float sm = 0.f;
        for (int j = 0; j < Kz; j++) sm += expf(alpha[j] + en[j] - mx);
        Zs[b] = mx + logf(sm);
    } else if (tid >= 64 && tid < 64 + Bz) {
        int b = tid - 64;
        const float* em = EM + (size_t)b * Tz * Kz;
        const int* mr = am + b * Lz;
        int* hb = hist + (size_t)b * (Tz - 1) * Kz;
        float sc[Kz];
#pragma unroll
        for (int j = 0; j < Kz; j++) sc[j] = st[j] + em[j];
        for (int t = 1; t < Tz; t++) {
            bool mm = mr[t + 1] != 0;
            float nxt[Kz]; int arg[Kz];
            for (int j = 0; j < Kz; j++) {
                float best = -1e30f; int bi = 0;
                for (int i = 0; i < Kz; i++) {
                    float v = sc[i] + tr[i * Kz + j];
                    if (v > best) { best = v; bi = i; }
                }
                nxt[j] = best + em[t * Kz + j]; arg[j] = bi;
            }
            for (int j = 0; j < Kz; j++) hb[(size_t)(t - 1) * Kz + j] = arg[j];
            if (mm) { for (int j = 0; j < Kz; j++) sc[j] = nxt[j]; }
        }
        float best = -1e30f; int last = 0;
        for (int j = 0; j < Kz; j++) { float v = sc[j] + en[j]; if (v > best) { best = v; last = j; } }
        int tag = last;
        for (int t = Tz - 2; t >= 0; t--) {
            out[1 + b * Tz + (t + 1)] = (float)tag;
            int prev = hb[(size_t)t * Kz + tag];
            if (mr[t + 2] != 0) tag = prev;
        }
        out[1 + b * Tz] = (float)tag;
    }
    __syncthreads();
    if (tid == 0) {
        float s = 0.f;
        for (int b = 0; b < Bz; b++) s += nums[b] - Zs[b];
        out[0] = s * (1.0f / Bz);
    }
}

extern "C" void kernel_launch(void* const* d_in, const int* in_sizes, int n_in,
                              void* d_out, int out_size, void* d_ws, size_t ws_size,
                              hipStream_t stream)
{
    (void)in_sizes; (void)n_in; (void)out_size; (void)ws_size;
    const int* ids    = (const int*)d_in[0];
    const int* amask  = (const int*)d_in[1];
    const int* tts    = (const int*)d_in[2];
    const int* ytrue  = (const int*)d_in[3];
    const float* we   = (const float*)d_in[4];
    const float* pe   = (const float*)d_in[5];
    const float* te   = (const float*)d_in[6];
    const float* eg   = (const float*)d_in[7];
    const float* eb   = (const float*)d_in[8];
    const float* Wq   = (const float*)d_in[9];
    const float* bq   = (const float*)d_in[10];
    const float* Wk   = (const float*)d_in[11];
    const float* bk   = (const float*)d_in[12];
    const float* Wv   = (const float*)d_in[13];
    const float* bv   = (const float*)d_in[14];
    const float* Wo   = (const float*)d_in[15];
    const float* bo   = (const float*)d_in[16];
    const float* ln1g = (const float*)d_in[17];
    const float* ln1b = (const float*)d_in[18];
    const float* W1   = (const float*)d_in[19];
    const float* b1   = (const float*)d_in[20];
    const float* W2   = (const float*)d_in[21];
    const float* b2   = (const float*)d_in[22];
    const float* ln2g = (const float*)d_in[23];
    const float* ln2b = (const float*)d_in[24];
    const float* hW   = (const float*)d_in[25];
    const float* hb   = (const float*)d_in[26];
    const float* cs   = (const float*)d_in[27];
    const float* ce   = (const float*)d_in[28];
    const float* ctr  = (const float*)d_in[29];

    float* ws = (float*)d_ws;
    size_t RDM = (size_t)RR * DMz;
    float* X  = ws;
    float* B1 = X  + RDM;      // B1..B3 double as fused QKV [4096][2304]
    float* B2 = B1 + RDM;
    float* B3 = B2 + RDM;
    float* B4 = B3 + RDM;
    float* F  = B2;            // 4096x1536 aliases B2+B3 exactly
    float* EM = B4 + RDM;
    int*  HIST = (int*)(EM + (size_t)Bz * Tz * Kz);
    float* BB  = (float*)(HIST + (size_t)Bz * (Tz - 1) * Kz); // 12x2304 QKV bias
    // total ws ≈ 5*RDM*4 + ~0.7MB ≈ 63.6 MB

    (void)hipGetLastError();
    sentinel_k<<<1, 64, 0, stream>>>((float*)d_out);
    embed_ln_k<<<RR, 256, 0, stream>>>(ids, tts, we, pe, te, eg, eb, X);
    bbfill_k<<<(NLz * QKVP + 255) / 256, 256, 0, stream>>>(bq, bk, bv, BB);

    for (int l = 0; l < NLz; l++) {
        size_t wofs = (size_t)l * DMz * DMz;
        // --- fused QKV: WT planes live in B4 (free) ---
        _Float16* wt4h = (_Float16*)B4;
        _Float16* wt4l = wt4h + (size_t)QKVP * DMz;
        wt_k<<<dim3(12, 12), 256, 0, stream>>>(Wq + wofs, DMz, DMz, DMz, wt4h, wt4l, 0, DMz);
        wt_k<<<dim3(12, 12), 256, 0, stream>>>(Wk + wofs, DMz, DMz, DMz, wt4h, wt4l, 768, DMz);
        wt_k<<<dim3(12, 12), 256, 0, stream>>>(Wv + wofs, DMz, DMz, DMz, wt4h, wt4l, 1536, DMz);
        gemm_mx_k<<<dim3(18, 32), 256, 0, stream>>>(X, DMz, wt4h, wt4l, BB + l * QKVP,
                                                    B1, QKVP, DMz, 0, 0);
        attn_k<<<Bz * NHz, 128, 0, stream>>>(B1, amask, B4); // overwrites WT (consumed)
        // --- O proj: WT in B1 (QKV consumed), out B2 ---
        _Float16* wt1h = (_Float16*)B1;
        _Float16* wt1l = wt1h + (size_t)DMz * DMz;
        wt_k<<<dim3(12, 12), 256, 0, stream>>>(Wo + wofs, DMz, DMz, DMz, wt1h, wt1l, 0, DMz);
        gemm_mx_k<<<dim3(6, 32), 256, 0, stream>>>(B4, DMz, wt1h, wt1l, bo + l * DMz,
                                                   B2, DMz, DMz, 0, 0);
        addln_k<<<RR, 256, 0, stream>>>(X, B2, ln1g + l * DMz, ln1b + l * DMz);
        // --- FFN in halves (F = B2B3 holds 4096x1536); WT planes in B1 ---
        const float* W1l = W1 + (size_t)l * DMz * FFz;
        const float* W2l = W2 + (size_t)l * FFz * DMz;
        const float* b1l = b1 + (size_t)l * FFz;
        _Float16* wtfh = (_Float16*)B1;
        _Float16* wtfl = wtfh + (size_t)1536 * DMz; // same plane size for FF1/FF2 WTs
        // half a
        wt_k<<<dim3(24, 12), 256, 0, stream>>>(W1l, FFz, DMz, 1536, wtfh, wtfl, 0, DMz);
        gemm_mx_k<<<dim3(12, 32), 256, 0, stream>>>(X, DMz, wtfh, wtfl, b1l,
                                                    F, 1536, DMz, 1, 0);
        wt_k<<<dim3(12, 24), 256, 0, stream>>>(W2l, DMz, 1536, DMz, wtfh, wtfl, 0, 1536);
        gemm_mx_k<<<dim3(6, 32), 256, 0, stream>>>(F, 1536, wtfh, wtfl, b2 + l * DMz,
                                                   B4, DMz, 1536, 0, 0);
        // half b
        wt_k<<<dim3(24, 12), 256, 0, stream>>>(W1l + 1536, FFz, DMz, 1536, wtfh, wtfl, 0, DMz);
        gemm_mx_k<<<dim3(12, 32), 256, 0, stream>>>(X, DMz, wtfh, wtfl, b1l + 1536,
                                                    F, 1536, DMz, 1, 0);
        wt_k<<<dim3(12, 24), 256, 0, stream>>>(W2l + (size_t)1536 * DMz, DMz, 1536, DMz,
                                               wtfh, wtfl, 0, 1536);
        gemm_mx_k<<<dim3(6, 32), 256, 0, stream>>>(F, 1536, wtfh, wtfl, nullptr,
                                                   B4, DMz, 1536, 0, 1);
        addln_k<<<RR, 256, 0, stream>>>(X, B4, ln2g + l * DMz, ln2b + l * DMz);
    }
    head_k<<<Bz * Tz, 64, 0, stream>>>(X, hW, hb, EM);
    crf_k<<<1, 128, 0, stream>>>(EM, ytrue, amask, cs, ce, ctr, HIST, (float*)d_out);

    if (hipGetLastError() != hipSuccess) {
        hipMemsetAsync(d_out, 0xFF, 4, stream); // out[0] -> f32 NaN signal
    }
}

// Round 2
// 7028.979 us; speedup vs baseline: 1.0078x; 1.0078x over previous
//
#include <hip/hip_runtime.h>
#include <math.h>

// NERBertWithCRF — round 6.
// r5: 20706 -> 7084 us (MFMA f16 hi/lo 3-term GEMM).
// r6: (a) CRF state-parallel rewrite (was 500us single-block serial);
//     (b) GEMM: chunk-major WT layout + global_load_lds(16B) double-buffered B,
//         chunk-major A LDS (sequential conflict-free ds_read_b128),
//         loads issued before compute so barrier drain overlaps MFMA (m97 pattern).

#define Bz 32
#define Lz 128
#define DMz 768
#define NLz 12
#define NHz 12
#define DHz 64
#define FFz 3072
#define Kz 9
#define Tz 127
#define RR (Bz * Lz) // 4096 rows
#define QKVP 2304    // fused QKV output pitch

typedef float f32x4v __attribute__((ext_vector_type(4)));
typedef _Float16 f16x8v __attribute__((ext_vector_type(8)));

__device__ __forceinline__ float wred(float v) {
#pragma unroll
    for (int o = 32; o > 0; o >>= 1) v += __shfl_down(v, o, 64);
    return v;
}

__device__ __forceinline__ void gload16(const void* g, void* l) {
    __builtin_amdgcn_global_load_lds(
        (const __attribute__((address_space(1))) void*)g,
        (__attribute__((address_space(3))) void*)l, 16, 0, 0);
}

__global__ void sentinel_k(float* out) {
    if (threadIdx.x == 0) out[0] = 123456.0f;
}

// ---------------- embedding + LayerNorm ----------------
__global__ __launch_bounds__(256) void embed_ln_k(
    const int* __restrict__ ids, const int* __restrict__ tts,
    const float* __restrict__ we, const float* __restrict__ pe, const float* __restrict__ te,
    const float* __restrict__ g, const float* __restrict__ bb, float* __restrict__ X)
{
    int r = blockIdx.x;
    int pos = r & (Lz - 1);
    int tid = threadIdx.x;
    int id = ids[r], tt = tts[r];
    __shared__ float buf[DMz];
    __shared__ float sa[4], sb[4];
    float s = 0.f, s2 = 0.f;
    for (int d = tid; d < DMz; d += 256) {
        float v = we[(size_t)id * DMz + d] + pe[pos * DMz + d] + te[tt * DMz + d];
        buf[d] = v; s += v; s2 += v * v;
    }
    float w1 = wred(s), w2 = wred(s2);
    if ((tid & 63) == 0) { sa[tid >> 6] = w1; sb[tid >> 6] = w2; }
    __syncthreads();
    float S = sa[0] + sa[1] + sa[2] + sa[3];
    float S2 = sb[0] + sb[1] + sb[2] + sb[3];
    float mean = S * (1.f / DMz);
    float var = S2 * (1.f / DMz) - mean * mean;
    float inv = rsqrtf(var + 1e-12f);
    for (int d = tid; d < DMz; d += 256)
        X[(size_t)r * DMz + d] = (buf[d] - mean) * inv * g[d] + bb[d];
}

// ---------------- residual add + LayerNorm (in-place into X) ----------------
__global__ __launch_bounds__(256) void addln_k(
    float* __restrict__ X, const float* __restrict__ Y,
    const float* __restrict__ g, const float* __restrict__ bb)
{
    int r = blockIdx.x;
    int tid = threadIdx.x;
    __shared__ float buf[DMz];
    __shared__ float sa[4], sb2[4];
    size_t base = (size_t)r * DMz;
    float s = 0.f, s2 = 0.f;
    for (int d = tid; d < DMz; d += 256) {
        float v = X[base + d] + Y[base + d];
        buf[d] = v; s += v; s2 += v * v;
    }
    float w1 = wred(s), w2 = wred(s2);
    if ((tid & 63) == 0) { sa[tid >> 6] = w1; sb2[tid >> 6] = w2; }
    __syncthreads();
    float S = sa[0] + sa[1] + sa[2] + sa[3];
    float S2 = sb2[0] + sb2[1] + sb2[2] + sb2[3];
    float mean = S * (1.f / DMz);
    float var = S2 * (1.f / DMz) - mean * mean;
    float inv = rsqrtf(var + 1e-12f);
    for (int d = tid; d < DMz; d += 256)
        X[base + d] = (buf[d] - mean) * inv * g[d] + bb[d];
}

// ---------------- QKV bias concat (all layers, once) ----------------
__global__ __launch_bounds__(256) void bbfill_k(
    const float* __restrict__ bq, const float* __restrict__ bk,
    const float* __restrict__ bv, float* __restrict__ BB)
{
    int i = blockIdx.x * 256 + threadIdx.x;
    if (i >= NLz * QKVP) return;
    int l = i / QKVP, j = i - l * QKVP;
    float v;
    if (j < 768) v = bq[l * 768 + j];
    else if (j < 1536) v = bk[l * 768 + j - 768];
    else v = bv[l * 768 + j - 1536];
    BB[i] = v;
}

// ---------------- weight -> chunk-major transposed hi/lo split ----------------
// W f32 [K][N] (pitch ldw). Output per (nb,kt) 128x32 tile = 8192 f16 elems:
//   chunk c = ((wc*2+p)*4+ni), elem off = (c*64+lane)*8 + kk,
//   n = nb*128 + wc*64 + ni*16 + (lane&15), k = kt*32 + (lane>>4)*8 + kk.
__global__ __launch_bounds__(256) void wt_k(
    const float* __restrict__ W, int ldw, _Float16* __restrict__ WT,
    int nkt, int nb0)
{
    __shared__ float LS[32][132];
    int nb = blockIdx.x, kt = blockIdx.y;
    int t = threadIdx.x;
    // load 32(k) x 128(n), coalesced along n
    int kr = t >> 3, nc = (t & 7) << 4;
    const float* wp = W + (size_t)(kt * 32 + kr) * ldw + nb * 128 + nc;
    float4 a = *(const float4*)wp;
    float4 b = *(const float4*)(wp + 4);
    float4 c4 = *(const float4*)(wp + 8);
    float4 d = *(const float4*)(wp + 12);
    float* q = &LS[kr][nc];
    q[0]=a.x;q[1]=a.y;q[2]=a.z;q[3]=a.w;
    q[4]=b.x;q[5]=b.y;q[6]=b.z;q[7]=b.w;
    q[8]=c4.x;q[9]=c4.y;q[10]=c4.z;q[11]=c4.w;
    q[12]=d.x;q[13]=d.y;q[14]=d.z;q[15]=d.w;
    __syncthreads();
    int lane = t & 63, w = t >> 6;
    _Float16* outb = WT + ((size_t)(nb0 + nb) * nkt + kt) * 8192;
#pragma unroll
    for (int j = 0; j < 4; j++) {
        int cc = w * 4 + j;                  // chunk 0..15
        int wc = cc >> 3, p = (cc >> 2) & 1, ni = cc & 3;
        int n = wc * 64 + ni * 16 + (lane & 15);
        int k8 = (lane >> 4) << 3;
        __align__(16) _Float16 bf[8];
#pragma unroll
        for (int jj = 0; jj < 8; jj++) {
            float v = LS[k8 + jj][n];
            _Float16 h = (_Float16)v;
            bf[jj] = p ? (_Float16)(v - (float)h) : h;
        }
        *(uint4*)&outb[(size_t)(cc * 64 + lane) * 8] = *(uint4*)&bf[0];
    }
}

// ---------------- MFMA GEMM: C = [accum +] act(A @ W + bias) ----------------
// A f32 [M][Kd] (pitch lda); WT chunk-major f16 (see wt_k).
// 128x128x32 tiles, 4 waves; A reg-staged+split to chunk-major LDS;
// B streamed via global_load_lds into double-buffered LDS, issued pre-compute.
__global__ __launch_bounds__(256) void gemm_mx_k(
    const float* __restrict__ A, int lda,
    const _Float16* __restrict__ WT,
    const float* __restrict__ bias, float* __restrict__ C, int ldc,
    int Kd, int act, int accum)
{
    __shared__ __align__(16) _Float16 Asm[8192];     // 16KB chunk-major A (hi+lo)
    __shared__ __align__(16) _Float16 Bsm[2][8192];  // 2x16KB chunk-major B
    int tid = threadIdx.x;
    int lane = tid & 63, w = tid >> 6;
    int wr = w >> 1, wc = w & 1;
    int row0 = blockIdx.y * 128, col0 = blockIdx.x * 128;
    int nk = Kd >> 5;
    // staging ids
    int sr = tid >> 1;                 // A row 0..127
    int sk = (tid & 1) << 4;           // k offset 0/16
    int swr = sr >> 6, smi = (sr >> 4) & 3, srr = sr & 15;
    int o0 = (tid & 1) << 1;           // k-octet base 0/2
    const float* ap = A + (size_t)(row0 + sr) * lda + sk;
    const _Float16* wtb = WT + (size_t)((col0 >> 7) * nk) * 8192 + (w << 11) + (lane << 3);
    int ldst = (w << 11) + (lane << 3);

    f32x4v acc[4][4];
#pragma unroll
    for (int i = 0; i < 4; i++)
#pragma unroll
        for (int j = 0; j < 4; j++) acc[i][j] = (f32x4v)0.f;

    __align__(16) float av[16];
#define LOADA(kt) do { \
        const float* _p = ap + ((kt) << 5); \
        *(float4*)&av[0]  = *(const float4*)(_p); \
        *(float4*)&av[4]  = *(const float4*)(_p + 4); \
        *(float4*)&av[8]  = *(const float4*)(_p + 8); \
        *(float4*)&av[12] = *(const float4*)(_p + 12); \
    } while (0)

    // prologue: A(0) to regs; B(0) -> Bsm[0]
    LOADA(0);
#pragma unroll
    for (int j = 0; j < 4; j++)
        gload16(wtb + (j << 9), &Bsm[0][ldst + (j << 9)]);

    int abase_hi = ((swr << 3) + smi) * 512;
    int abase_lo = abase_hi + 2048;

    for (int kt = 0; kt < nk; ++kt) {
        __syncthreads();   // (1) prev reads done; drains B(kt)+A-regs(kt)
        {
            __align__(16) _Float16 hh[16], ll[16];
#pragma unroll
            for (int i = 0; i < 16; i++) {
                _Float16 h = (_Float16)av[i];
                hh[i] = h;
                ll[i] = (_Float16)(av[i] - (float)h);
            }
            *(uint4*)&Asm[abase_hi + ((o0    ) * 16 + srr) * 8] = *(uint4*)&hh[0];
            *(uint4*)&Asm[abase_hi + ((o0 + 1) * 16 + srr) * 8] = *(uint4*)&hh[8];
            *(uint4*)&Asm[abase_lo + ((o0    ) * 16 + srr) * 8] = *(uint4*)&ll[0];
            *(uint4*)&Asm[abase_lo + ((o0 + 1) * 16 + srr) * 8] = *(uint4*)&ll[8];
        }
        __syncthreads();   // (2) A visible; nothing in vmem queue -> cheap
        if (kt + 1 < nk) {
            const _Float16* ts = wtb + (size_t)(kt + 1) * 8192;
            _Float16* db = &Bsm[(kt + 1) & 1][ldst];
#pragma unroll
            for (int j = 0; j < 4; j++)
                gload16(ts + (j << 9), db + (j << 9));
            LOADA(kt + 1);
        }
        // compute tile kt
        const _Float16* Bc = &Bsm[kt & 1][0];
        f16x8v afh[4], afl[4];
#pragma unroll
        for (int mi = 0; mi < 4; mi++) {
            afh[mi] = *(const f16x8v*)&Asm[(((wr << 1) + 0) * 4 + mi) * 512 + (lane << 3)];
            afl[mi] = *(const f16x8v*)&Asm[(((wr << 1) + 1) * 4 + mi) * 512 + (lane << 3)];
        }
#pragma unroll
        for (int ni = 0; ni < 4; ni++) {
            f16x8v bfh = *(const f16x8v*)&Bc[(((wc << 1) + 0) * 4 + ni) * 512 + (lane << 3)];
            f16x8v bfl = *(const f16x8v*)&Bc[(((wc << 1) + 1) * 4 + ni) * 512 + (lane << 3)];
#pragma unroll
            for (int mi = 0; mi < 4; mi++) {
                acc[mi][ni] = __builtin_amdgcn_mfma_f32_16x16x32_f16(afh[mi], bfh, acc[mi][ni], 0, 0, 0);
                acc[mi][ni] = __builtin_amdgcn_mfma_f32_16x16x32_f16(afh[mi], bfl, acc[mi][ni], 0, 0, 0);
                acc[mi][ni] = __builtin_amdgcn_mfma_f32_16x16x32_f16(afl[mi], bfh, acc[mi][ni], 0, 0, 0);
            }
        }
    }
#undef LOADA

    // epilogue: C/D layout (16x16): col = lane&15, row = (lane>>4)*4 + reg
    int rb2 = (lane >> 4) << 2;
    int cb = lane & 15;
#pragma unroll
    for (int mi = 0; mi < 4; mi++) {
#pragma unroll
        for (int ni = 0; ni < 4; ni++) {
            int cc = col0 + wc * 64 + ni * 16 + cb;
            float bv = bias ? bias[cc] : 0.f;
#pragma unroll
            for (int r = 0; r < 4; r++) {
                int rr = row0 + wr * 64 + mi * 16 + rb2 + r;
                float v = acc[mi][ni][r] + bv;
                if (act == 1) v = 0.5f * v * (1.0f + erff(v * 0.70710678118f));
                size_t o = (size_t)rr * ldc + cc;
                if (accum) v += C[o];
                C[o] = v;
            }
        }
    }
}

// ---------------- attention: flash-style, one block per (b,h) ----------------
__global__ __launch_bounds__(128) void attn_k(
    const float* __restrict__ QKV, const int* __restrict__ am, float* __restrict__ CTX)
{
    int bh = blockIdx.x;
    int b = bh / NHz, h = bh - b * NHz;
    __shared__ float Ks[64][DHz];
    __shared__ float Vs[64][DHz];
    int tid = threadIdx.x;
    float qreg[DHz];
    {
        const float* qp = QKV + (size_t)(b * Lz + tid) * QKVP + h * DHz;
#pragma unroll
        for (int d = 0; d < DHz; d++) qreg[d] = qp[d];
    }
    float m = -INFINITY, l = 0.f;
    float ctx[DHz];
#pragma unroll
    for (int d = 0; d < DHz; d++) ctx[d] = 0.f;
    for (int kc = 0; kc < Lz; kc += 64) {
        __syncthreads();
        for (int i = tid; i < 64 * DHz; i += 128) {
            int kk = i >> 6, d = i & 63;
            size_t base = (size_t)(b * Lz + kc + kk) * QKVP + h * DHz + d;
            Ks[kk][d] = QKV[base + 768];
            Vs[kk][d] = QKV[base + 1536];
        }
        __syncthreads();
        for (int k = 0; k < 64; k++) {
            float s = 0.f;
#pragma unroll
            for (int d = 0; d < DHz; d++) s = fmaf(qreg[d], Ks[k][d], s);
            s = s * 0.125f + (1.0f - (float)am[b * Lz + kc + k]) * -1e9f;
            float nm = fmaxf(m, s);
            float alpha = __expf(m - nm);
            float p = __expf(s - nm);
            l = l * alpha + p;
#pragma unroll
            for (int d = 0; d < DHz; d++) ctx[d] = ctx[d] * alpha + p * Vs[k][d];
            m = nm;
        }
    }
    float inv = 1.0f / l;
    float* cp = CTX + (size_t)(b * Lz + tid) * DMz + h * DHz;
#pragma unroll
    for (int d = 0; d < DHz; d++) cp[d] = ctx[d] * inv;
}

// ---------------- head: em[b,t,:] = x[b,t+1,:] @ head_W + head_b ----------------
__global__ __launch_bounds__(64) void head_k(
    const float* __restrict__ X, const float* __restrict__ hW, const float* __restrict__ hb,
    float* __restrict__ EM)
{
    int rt = blockIdx.x;
    int b = rt / Tz, t = rt - b * Tz;
    int lane = threadIdx.x;
    const float* xp = X + (size_t)(b * Lz + t + 1) * DMz;
    float acc[Kz];
#pragma unroll
    for (int k = 0; k < Kz; k++) acc[k] = 0.f;
    for (int d = lane; d < DMz; d += 64) {
        float xv = xp[d];
#pragma unroll
        for (int k = 0; k < Kz; k++) acc[k] = fmaf(xv, hW[d * Kz + k], acc[k]);
    }
#pragma unroll
    for (int k = 0; k < Kz; k++) acc[k] = wred(acc[k]);
    if (lane == 0) {
#pragma unroll
        for (int k = 0; k < Kz; k++) EM[(size_t)rt * Kz + k] = acc[k] + hb[k];
    }
}

// ---------------- CRF: block per batch; wave0 = forward/llh, wave1 = viterbi ----------------
__global__ __launch_bounds__(128) void crf_k(
    const float* __restrict__ EM, const int* __restrict__ yt, const int* __restrict__ am,
    const float* __restrict__ cs, const float* __restrict__ ce, const float* __restrict__ ctr,
    float* __restrict__ part, float* __restrict__ out)
{
    int b = blockIdx.x;
    int tid = threadIdx.x;
    int lane = tid & 63, wv = tid >> 6;
    __shared__ float em_s[Tz * Kz];
    __shared__ float tr_s[Kz * Kz], st_s[Kz], en_s[Kz];
    __shared__ int y_s[Tz], mk_s[Lz];
    __shared__ int hist_s[(Tz - 1) * Kz];
    const float* em = EM + (size_t)b * Tz * Kz;
    for (int i = tid; i < Tz * Kz; i += 128) em_s[i] = em[i];
    if (tid < Kz * Kz) tr_s[tid] = ctr[tid];
    if (tid < Kz) { st_s[tid] = cs[tid]; en_s[tid] = ce[tid]; }
    for (int i = tid; i < Tz; i += 128) y_s[i] = yt[b * Tz + i];
    for (int i = tid; i < Lz; i += 128) mk_s[i] = am[b * Lz + i];
    __syncthreads();
    int jj = (lane < Kz) ? lane : 0;
    if (wv == 0) {
        // numerator: lane-parallel over t
        float np = 0.f;
        for (int t = 1 + lane; t < Tz; t += 64)
            if (mk_s[t + 1] != 0)
                np += tr_s[y_s[t - 1] * Kz + y_s[t]] + em_s[t * Kz + y_s[t]];
        float cnt = 0.f;
        for (int t = lane; t < Tz; t += 64) cnt += (mk_s[t + 1] != 0) ? 1.f : 0.f;
        np = wred(np);
        cnt = wred(cnt);
        // forward recurrence, state-parallel lanes 0..8
        float trc[Kz];
#pragma unroll
        for (int i = 0; i < Kz; i++) trc[i] = tr_s[i * Kz + jj];
        float alpha = (lane < Kz) ? st_s[lane] + em_s[lane] : 0.f;
        for (int t = 1; t < Tz; t++) {
            float vv[Kz], mx = -1e30f;
#pragma unroll
            for (int i = 0; i < Kz; i++) {
                float ai = __shfl(alpha, i, 64);
                vv[i] = ai + trc[i];
                mx = fmaxf(mx, vv[i]);
            }
            float sm = 0.f;
#pragma unroll
            for (int i = 0; i < Kz; i++) sm += __expf(vv[i] - mx);
            float nx = mx + __logf(sm) + em_s[t * Kz + jj];
            if (mk_s[t + 1] != 0) alpha = nx;
        }
        float zvl = alpha + en_s[jj];
        float zz[Kz], zmx = -1e30f, zsm = 0.f;
#pragma unroll
        for (int i = 0; i < Kz; i++) {
            zz[i] = __shfl(zvl, i, 64);
            zmx = fmaxf(zmx, zz[i]);
        }
#pragma unroll
        for (int i = 0; i < Kz; i++) zsm += __expf(zz[i] - zmx);
        if (lane == 0) {
            int lastidx = (int)cnt - 1;
            float num = st_s[y_s[0]] + em_s[y_s[0]] + np + en_s[y_s[lastidx]];
            part[b] = num - (zmx + __logf(zsm));
        }
    } else {
        // viterbi, state-parallel lanes 0..8
        float trc[Kz];
#pragma unroll
        for (int i = 0; i < Kz; i++) trc[i] = tr_s[i * Kz + jj];
        float sc = (lane < Kz) ? st_s[lane] + em_s[lane] : -1e30f;
        for (int t = 1; t < Tz; t++) {
            float best = -1e30f; int bi = 0;
#pragma unroll
            for (int i = 0; i < Kz; i++) {
                float v = __shfl(sc, i, 64) + trc[i];
                if (v > best) { best = v; bi = i; }
            }
            if (lane < Kz) hist_s[(t - 1) * Kz + lane] = bi;
            float nx = best + em_s[t * Kz + jj];
            if (mk_s[t + 1] != 0) sc = nx;
        }
        float bestv = -1e30f; int last = 0;
#pragma unroll
        for (int j = 0; j < Kz; j++) {
            float v = __shfl(sc, j, 64) + en_s[j];
            if (v > bestv) { bestv = v; last = j; }
        }
        if (lane == 0) {
            int tag = last;
            for (int t = Tz - 2; t >= 0; t--) {
                out[1 + b * Tz + (t + 1)] = (float)tag;
                int prev = hist_s[t * Kz + tag];
                if (mk_s[t + 2] != 0) tag = prev;
            }
            out[1 + b * Tz] = (float)tag;
        }
    }
}

__global__ __launch_bounds__(64) void crffin_k(const float* __restrict__ part, float* __restrict__ out) {
    int lane = threadIdx.x;
    float v = (lane < Bz) ? part[lane] : 0.f;
    v = wred(v);
    if (lane == 0) out[0] = v * (1.0f / Bz);
}

extern "C" void kernel_launch(void* const* d_in, const int* in_sizes, int n_in,
                              void* d_out, int out_size, void* d_ws, size_t ws_size,
                              hipStream_t stream)
{
    (void)in_sizes; (void)n_in; (void)out_size; (void)ws_size;
    const int* ids    = (const int*)d_in[0];
    const int* amask  = (const int*)d_in[1];
    const int* tts    = (const int*)d_in[2];
    const int* ytrue  = (const int*)d_in[3];
    const float* we   = (const float*)d_in[4];
    const float* pe   = (const float*)d_in[5];
    const float* te   = (const float*)d_in[6];
    const float* eg   = (const float*)d_in[7];
    const float* eb   = (const float*)d_in[8];
    const float* Wq   = (const float*)d_in[9];
    const float* bq   = (const float*)d_in[10];
    const float* Wk   = (const float*)d_in[11];
    const float* bk   = (const float*)d_in[12];
    const float* Wv   = (const float*)d_in[13];
    const float* bv   = (const float*)d_in[14];
    const float* Wo   = (const float*)d_in[15];
    const float* bo   = (const float*)d_in[16];
    const float* ln1g = (const float*)d_in[17];
    const float* ln1b = (const float*)d_in[18];
    const float* W1   = (const float*)d_in[19];
    const float* b1   = (const float*)d_in[20];
    const float* W2   = (const float*)d_in[21];
    const float* b2   = (const float*)d_in[22];
    const float* ln2g = (const float*)d_in[23];
    const float* ln2b = (const float*)d_in[24];
    const float* hW   = (const float*)d_in[25];
    const float* hb   = (const float*)d_in[26];
    const float* cs   = (const float*)d_in[27];
    const float* ce   = (const float*)d_in[28];
    const float* ctr  = (const float*)d_in[29];

    float* ws = (float*)d_ws;
    size_t RDM = (size_t)RR * DMz;
    float* X  = ws;
    float* B1 = X  + RDM;      // B1..B3 double as fused QKV [4096][2304]
    float* B2 = B1 + RDM;
    float* B3 = B2 + RDM;
    float* B4 = B3 + RDM;
    float* F  = B2;            // 4096x1536 aliases B2+B3 exactly
    float* EM = B4 + RDM;
    float* PART = EM + (size_t)Bz * Tz * Kz;
    float* BB   = PART + 64;   // 12x2304 QKV bias
    // total ws ≈ 5*RDM*4 + ~0.6MB ≈ 63.5 MB

    (void)hipGetLastError();
    sentinel_k<<<1, 64, 0, stream>>>((float*)d_out);
    embed_ln_k<<<RR, 256, 0, stream>>>(ids, tts, we, pe, te, eg, eb, X);
    bbfill_k<<<(NLz * QKVP + 255) / 256, 256, 0, stream>>>(bq, bk, bv, BB);

    for (int l = 0; l < NLz; l++) {
        size_t wofs = (size_t)l * DMz * DMz;
        // --- fused QKV: WT (chunk-major) in B4 (free) ---
        _Float16* wt4 = (_Float16*)B4;   // 18*24*8192*2B = 7.08MB
        wt_k<<<dim3(6, 24), 256, 0, stream>>>(Wq + wofs, DMz, wt4, 24, 0);
        wt_k<<<dim3(6, 24), 256, 0, stream>>>(Wk + wofs, DMz, wt4, 24, 6);
        wt_k<<<dim3(6, 24), 256, 0, stream>>>(Wv + wofs, DMz, wt4, 24, 12);
        gemm_mx_k<<<dim3(18, 32), 256, 0, stream>>>(X, DMz, wt4, BB + l * QKVP,
                                                    B1, QKVP, DMz, 0, 0);
        attn_k<<<Bz * NHz, 128, 0, stream>>>(B1, amask, B4); // overwrites WT (consumed)
        // --- O proj: WT in B1 (QKV consumed), out B2 ---
        _Float16* wt1 = (_Float16*)B1;
        wt_k<<<dim3(6, 24), 256, 0, stream>>>(Wo + wofs, DMz, wt1, 24, 0);
        gemm_mx_k<<<dim3(6, 32), 256, 0, stream>>>(B4, DMz, wt1, bo + l * DMz,
                                                   B2, DMz, DMz, 0, 0);
        addln_k<<<RR, 256, 0, stream>>>(X, B2, ln1g + l * DMz, ln1b + l * DMz);
        // --- FFN in halves (F = B2B3 holds 4096x1536); WTs in B1 ---
        const float* W1l = W1 + (size_t)l * DMz * FFz;
        const float* W2l = W2 + (size_t)l * FFz * DMz;
        const float* b1l = b1 + (size_t)l * FFz;
        // half a
        wt_k<<<dim3(12, 24), 256, 0, stream>>>(W1l, FFz, wt1, 24, 0);
        gemm_mx_k<<<dim3(12, 32), 256, 0, stream>>>(X, DMz, wt1, b1l,
                                                    F, 1536, DMz, 1, 0);
        wt_k<<<dim3(6, 48), 256, 0, stream>>>(W2l, DMz, wt1, 48, 0);
        gemm_mx_k<<<dim3(6, 32), 256, 0, stream>>>(F, 1536, wt1, b2 + l * DMz,
                                                   B4, DMz, 1536, 0, 0);
        // half b
        wt_k<<<dim3(12, 24), 256, 0, stream>>>(W1l + 1536, FFz, wt1, 24, 0);
        gemm_mx_k<<<dim3(12, 32), 256, 0, stream>>>(X, DMz, wt1, b1l + 1536,
                                                    F, 1536, DMz, 1, 0);
        wt_k<<<dim3(6, 48), 256, 0, stream>>>(W2l + (size_t)1536 * DMz, DMz, wt1, 48, 0);
        gemm_mx_k<<<dim3(6, 32), 256, 0, stream>>>(F, 1536, wt1, nullptr,
                                                   B4, DMz, 1536, 0, 1);
        addln_k<<<RR, 256, 0, stream>>>(X, B4, ln2g + l * DMz, ln2b + l * DMz);
    }
    head_k<<<Bz * Tz, 64, 0, stream>>>(X, hW, hb, EM);
    crf_k<<<Bz, 128, 0, stream>>>(EM, ytrue, amask, cs, ce, ctr, PART, (float*)d_out);
    crffin_k<<<1, 64, 0, stream>>>(PART, (float*)d_out);

    if (hipGetLastError() != hipSuccess) {
        hipMemsetAsync(d_out, 0xFF, 4, stream); // out[0] -> f32 NaN signal
    }
}